// Round 1
// baseline (284.756 us; speedup 1.0000x reference)
//
#include <hip/hip_runtime.h>
#include <cmath>

// Sinkhorn divergence (geomloss-style, debiased) between softmax rows.
// Pipeline:
//  1) gram_kernel: one pass over all inputs; per pair accumulates
//     Gxy/Gxx/Gyy (16x16 each) and row sums Zx,Zy of ex=exp(t).
//     fp32 exp + fp32 per-thread partials; per-block partial records (fp32)
//     written to ws (or fp64 atomics fallback if ws too small).
//  2) reduce_kernel: fp64 reduction of block partials -> final Gram (double).
//  3) sinkhorn_kernel: 6 blocks x 64 threads, register-resident 60-step loop,
//     fp32 + expm1/log1p polynomials (exact identity: LSE_j(logw+d_j) =
//     log1p(mean_j expm1(d_j)) since logw = -log(16)).
//  4) finalize_kernel: combine 3 pair divergences -> d_out.

#define TPB 256
#define CHUNK 256
#define COLS_PER_BLOCK 1024
#define STRIDE 20      // LDS floats per column record: 16 rows + 4 pad
#define NSTEP 60

struct EpsList { float e[NSTEP]; };

struct GramArgs {
  const float* x0; const float* y0;
  const float* x1; const float* y1;
  const float* x2; const float* y2;
  int M0, M1, M2;
  int bs1, bs2;      // first block id of pair 1 / pair 2
  float* partial;    // [numBlocks][800] fp32, or null in atomic mode
  double* finalG;    // [3][800] doubles
  int atomicMode;
};

__global__ __launch_bounds__(TPB) void gram_kernel(GramArgs A) {
  __shared__ __align__(16) float sEx[CHUNK * STRIDE];
  __shared__ __align__(16) float sEy[CHUNK * STRIDE];

  const int bid = blockIdx.x;
  int p, lb;
  if (bid >= A.bs2)      { p = 2; lb = bid - A.bs2; }
  else if (bid >= A.bs1) { p = 1; lb = bid - A.bs1; }
  else                   { p = 0; lb = bid; }
  const float* X = (p == 0) ? A.x0 : (p == 1) ? A.x1 : A.x2;
  const float* Y = (p == 0) ? A.y0 : (p == 1) ? A.y1 : A.y2;
  const int M    = (p == 0) ? A.M0 : (p == 1) ? A.M1 : A.M2;

  const int t     = threadIdx.x;
  const int slice = t & 15;     // reduction lanes (bits 0..3)
  const int tile  = t >> 4;     // 16 4x4 tiles covering 16x16
  const int ti    = tile >> 2;
  const int tk    = tile & 3;

  float axy[4][4] = {};
  float axx[4][4] = {};
  float ayy[4][4] = {};
  float zx[16] = {};
  float zy[16] = {};

  const size_t colbase = (size_t)lb * COLS_PER_BLOCK;

  #pragma unroll 1
  for (int ch = 0; ch < COLS_PER_BLOCK / CHUNK; ++ch) {
    const size_t c0 = colbase + (size_t)ch * CHUNK;
    // ---- phase 1: global -> exp -> LDS (transposed [col][row], pad 20) ----
    {
      const float* xp = X + c0 + (size_t)t;
      const float* yp = Y + c0 + (size_t)t;
      float vx[16], vy[16];
      #pragma unroll
      for (int r = 0; r < 16; ++r) {
        vx[r] = expf(xp[0]);
        vy[r] = expf(yp[0]);
        xp += M; yp += M;
      }
      #pragma unroll
      for (int r = 0; r < 16; ++r) { zx[r] += vx[r]; zy[r] += vy[r]; }
      #pragma unroll
      for (int q = 0; q < 4; ++q) {
        *reinterpret_cast<float4*>(&sEx[t * STRIDE + 4 * q]) =
            make_float4(vx[4*q], vx[4*q+1], vx[4*q+2], vx[4*q+3]);
        *reinterpret_cast<float4*>(&sEy[t * STRIDE + 4 * q]) =
            make_float4(vy[4*q], vy[4*q+1], vy[4*q+2], vy[4*q+3]);
      }
    }
    __syncthreads();
    // ---- phase 2: 4x4 register-tile outer products ----
    #pragma unroll
    for (int s = 0; s < 16; ++s) {
      const int c = slice + 16 * s;
      const float4 xi = *reinterpret_cast<const float4*>(&sEx[c * STRIDE + 4 * ti]);
      const float4 xk = *reinterpret_cast<const float4*>(&sEx[c * STRIDE + 4 * tk]);
      const float4 yi = *reinterpret_cast<const float4*>(&sEy[c * STRIDE + 4 * ti]);
      const float4 yk = *reinterpret_cast<const float4*>(&sEy[c * STRIDE + 4 * tk]);
      const float xiA[4] = {xi.x, xi.y, xi.z, xi.w};
      const float xkA[4] = {xk.x, xk.y, xk.z, xk.w};
      const float yiA[4] = {yi.x, yi.y, yi.z, yi.w};
      const float ykA[4] = {yk.x, yk.y, yk.z, yk.w};
      #pragma unroll
      for (int r = 0; r < 4; ++r) {
        #pragma unroll
        for (int u = 0; u < 4; ++u) {
          axy[r][u] = fmaf(xiA[r], ykA[u], axy[r][u]);
          axx[r][u] = fmaf(xiA[r], xkA[u], axx[r][u]);
          ayy[r][u] = fmaf(yiA[r], ykA[u], ayy[r][u]);
        }
      }
    }
    __syncthreads();
  }

  // ---- reduce tiles across slice lanes (bits 0..3), write partials ----
  float* rec = A.atomicMode ? nullptr : (A.partial + (size_t)bid * 800);
  double* fin = A.finalG + p * 800;
  #pragma unroll
  for (int r = 0; r < 4; ++r) {
    #pragma unroll
    for (int u = 0; u < 4; ++u) {
      float v0 = axy[r][u], v1 = axx[r][u], v2 = ayy[r][u];
      #pragma unroll
      for (int d = 1; d <= 8; d <<= 1) {
        v0 += __shfl_xor(v0, d);
        v1 += __shfl_xor(v1, d);
        v2 += __shfl_xor(v2, d);
      }
      if (slice == 0) {
        const int idx = (4 * ti + r) * 16 + (4 * tk + u);
        if (A.atomicMode) {
          atomicAdd(&fin[idx],       (double)v0);
          atomicAdd(&fin[256 + idx], (double)v1);
          atomicAdd(&fin[512 + idx], (double)v2);
        } else {
          rec[idx] = v0; rec[256 + idx] = v1; rec[512 + idx] = v2;
        }
      }
    }
  }
  // ---- Z reduce: full-wave butterfly, then cross-wave via LDS ----
  #pragma unroll
  for (int r = 0; r < 16; ++r) {
    #pragma unroll
    for (int d = 1; d <= 32; d <<= 1) {
      zx[r] += __shfl_xor(zx[r], d);
      zy[r] += __shfl_xor(zy[r], d);
    }
  }
  if ((t & 63) == 0) {
    const int w = t >> 6;
    #pragma unroll
    for (int r = 0; r < 16; ++r) {
      sEx[w * 32 + r]      = zx[r];
      sEx[w * 32 + 16 + r] = zy[r];
    }
  }
  __syncthreads();
  if (t < 32) {
    const float s = sEx[t] + sEx[32 + t] + sEx[64 + t] + sEx[96 + t];
    if (A.atomicMode) atomicAdd(&fin[768 + t], (double)s);
    else              rec[768 + t] = s;
  }
}

__global__ __launch_bounds__(256) void reduce_kernel(const float* __restrict__ partial,
                                                     double* __restrict__ finalG,
                                                     int nb0, int nb1, int nb2) {
  const int p   = blockIdx.x >> 6;
  const int k   = blockIdx.x & 63;
  const int cnt = (p == 0) ? nb0 : (p == 1) ? nb1 : nb2;
  const int st  = (p == 0) ? 0   : (p == 1) ? nb0 : nb0 + nb1;
  for (int v = threadIdx.x; v < 800; v += 256) {
    double s = 0.0;
    for (int r = k; r < cnt; r += 64)
      s += (double)partial[(size_t)(st + r) * 800 + v];
    atomicAdd(&finalG[p * 800 + v], s);
  }
}

__device__ __forceinline__ float expm1_poly(float d) {
  float p = 1.0f / 120.0f;
  p = fmaf(p, d, 1.0f / 24.0f);
  p = fmaf(p, d, 1.0f / 6.0f);
  p = fmaf(p, d, 0.5f);
  return fmaf(d * d, p, d);
}
__device__ __forceinline__ float log1p_poly(float w) {
  float p = -1.0f / 6.0f;
  p = fmaf(p, w, 1.0f / 5.0f);
  p = fmaf(p, w, -1.0f / 4.0f);
  p = fmaf(p, w, 1.0f / 3.0f);
  p = fmaf(p, w, -0.5f);
  return fmaf(w * w, p, w);
}

// blocks: 2p   -> (f,g) interlocked chains of pair p
//         2p+1 -> (a,b) self chains of pair p
// lane = pot*32 + i*2 + jh : pot in {0,1}, i row, jh half of the 16 j-terms
__global__ __launch_bounds__(64) void sinkhorn_kernel(const double* __restrict__ finalG,
                                                      double* __restrict__ result,
                                                      EpsList E) {
  const int p    = blockIdx.x >> 1;
  const int half = blockIdx.x & 1;
  const int lane = threadIdx.x;
  const int pot  = lane >> 5;
  const int i    = (lane >> 1) & 15;
  const int jh   = lane & 1;
  const double* G = finalG + p * 800;

  float Crow[8];
  #pragma unroll
  for (int jj = 0; jj < 8; ++jj) {
    const int j = jh * 8 + jj;
    double Cv;
    if (half == 0) {
      const int r = (pot == 0) ? i : j;   // Cxy for ft, Cxy^T for gt
      const int c = (pot == 0) ? j : i;
      const double zr = G[768 + r], zc = G[784 + c];
      const double sr = G[256 + 17 * r] / (zr * zr);
      const double sc = G[512 + 17 * c] / (zc * zc);
      Cv = 0.5 * (sr + sc) - G[16 * r + c] / (zr * zc);
    } else if (pot == 0) {               // Cxx
      const double zi_ = G[768 + i], zj_ = G[768 + j];
      const double si_ = G[256 + 17 * i] / (zi_ * zi_);
      const double sj_ = G[256 + 17 * j] / (zj_ * zj_);
      Cv = 0.5 * (si_ + sj_) - G[256 + 16 * i + j] / (zi_ * zj_);
    } else {                             // Cyy
      const double zi_ = G[784 + i], zj_ = G[784 + j];
      const double si_ = G[512 + 17 * i] / (zi_ * zi_);
      const double sj_ = G[512 + 17 * j] / (zj_ * zj_);
      Cv = 0.5 * (si_ + sj_) - G[512 + 16 * i + j] / (zi_ * zj_);
    }
    Crow[jj] = (float)Cv;
  }

  // source lane base: ft reads g, gt reads f; at reads a, bt reads b.
  const int srcBase = (half == 0) ? ((pot == 0) ? 32 : 0)
                                  : ((pot == 0) ? 0 : 32);
  float h = 0.0f;

  #pragma unroll 1
  for (int n = 0; n < NSTEP; ++n) {
    const float eps  = E.e[n];
    const float inve = 1.0f / eps;
    float q = 0.0f;
    #pragma unroll
    for (int jj = 0; jj < 8; ++jj) {
      const float hj = __shfl(h, srcBase + 2 * (jh * 8 + jj));
      q += expm1_poly((hj - Crow[jj]) * inve);
    }
    q += __shfl_xor(q, 1);
    const float val = -eps * log1p_poly(q * (1.0f / 16.0f));
    h = 0.5f * (h + val);
  }
  { // final extrapolation at eps = blur^p, no averaging
    const float eps  = 0.0025f;
    const float inve = 1.0f / eps;
    float q = 0.0f;
    #pragma unroll
    for (int jj = 0; jj < 8; ++jj) {
      const float hj = __shfl(h, srcBase + 2 * (jh * 8 + jj));
      q += expm1_poly((hj - Crow[jj]) * inve);
    }
    q += __shfl_xor(q, 1);
    h = -eps * log1p_poly(q * (1.0f / 16.0f));
  }
  // sum over 64 lanes (each (pot,i) counted twice) -> (sum pot0 + sum pot1)/16
  float s = h;
  #pragma unroll
  for (int d = 1; d <= 32; d <<= 1) s += __shfl_xor(s, d);
  if (lane == 0) result[blockIdx.x] = (double)(s * (1.0f / 32.0f));
}

__global__ void finalize_kernel(const double* __restrict__ result, float* __restrict__ out) {
  const double s = (result[0] - result[1]) + (result[2] - result[3]) + (result[4] - result[5]);
  out[0] = (float)(s / 3.0);
}

extern "C" void kernel_launch(void* const* d_in, const int* in_sizes, int n_in,
                              void* d_out, int out_size, void* d_ws, size_t ws_size,
                              hipStream_t stream) {
  // Pair the 6 inputs by size (desc); within a pair order is irrelevant
  // (the Sinkhorn divergence is symmetric in x,y).
  int idx[6] = {0, 1, 2, 3, 4, 5};
  for (int a = 1; a < 6; ++a) {
    const int key = idx[a];
    int b = a - 1;
    while (b >= 0 && in_sizes[idx[b]] < in_sizes[key]) { idx[b + 1] = idx[b]; --b; }
    idx[b + 1] = key;
  }

  const float* xs[3]; const float* ys[3]; int Ms[3]; int nb[3];
  for (int p = 0; p < 3; ++p) {
    xs[p] = (const float*)d_in[idx[2 * p]];
    ys[p] = (const float*)d_in[idx[2 * p + 1]];
    Ms[p] = in_sizes[idx[2 * p]] / 16;
    nb[p] = Ms[p] / COLS_PER_BLOCK;
  }
  const int totalBlocks = nb[0] + nb[1] + nb[2];

  const size_t partialBytes = (size_t)totalBlocks * 800 * sizeof(float);
  const size_t finalBytes   = (size_t)(2400 + 8) * sizeof(double);
  const bool partialMode    = (ws_size >= partialBytes + finalBytes);

  char* wsb      = (char*)d_ws;
  float* partial = partialMode ? (float*)wsb : nullptr;
  double* finalG = (double*)(wsb + (partialMode ? partialBytes : 0));
  double* result = finalG + 2400;

  hipMemsetAsync(finalG, 0, finalBytes, stream);

  GramArgs A;
  A.x0 = xs[0]; A.y0 = ys[0];
  A.x1 = xs[1]; A.y1 = ys[1];
  A.x2 = xs[2]; A.y2 = ys[2];
  A.M0 = Ms[0]; A.M1 = Ms[1]; A.M2 = Ms[2];
  A.bs1 = nb[0]; A.bs2 = nb[0] + nb[1];
  A.partial = partial; A.finalG = finalG;
  A.atomicMode = partialMode ? 0 : 1;

  gram_kernel<<<dim3(totalBlocks), dim3(TPB), 0, stream>>>(A);
  if (partialMode)
    reduce_kernel<<<dim3(192), dim3(256), 0, stream>>>(partial, finalG, nb[0], nb[1], nb[2]);

  EpsList E;
  const double base = 0.95 * 0.95;   // matches numpy's (SCALING**P)
  for (int n = 0; n < NSTEP; ++n) {
    double v = pow(base, (double)n);
    if (v < 0.0025) v = 0.0025;
    E.e[n] = (float)v;
  }
  sinkhorn_kernel<<<dim3(6), dim3(64), 0, stream>>>(finalG, result, E);
  finalize_kernel<<<dim3(1), dim3(1), 0, stream>>>(result, (float*)d_out);
}